// Round 12
// baseline (262.637 us; speedup 1.0000x reference)
//
#include <hip/hip_runtime.h>
#include <hip/hip_bf16.h>
#include <math.h>

#define D_MODEL 768
#define N_HEAD  12
#define SEQ     2048
#define BATCH   4
#define HD      64
#define BH      (BATCH*N_HEAD)

typedef __bf16 bf16;
typedef __bf16 bf16x4 __attribute__((ext_vector_type(4)));
typedef __bf16 bf16x8 __attribute__((ext_vector_type(8)));
typedef float  f32x4  __attribute__((ext_vector_type(4)));
typedef float  f32x16 __attribute__((ext_vector_type(16)));
typedef unsigned int u32;

__device__ __forceinline__ f32x4 mfma16(bf16x8 a, bf16x8 b, f32x4 c) {
    return __builtin_amdgcn_mfma_f32_16x16x32_bf16(a, b, c, 0, 0, 0);
}
__device__ __forceinline__ f32x16 mfma32(bf16x8 a, bf16x8 b, f32x16 c) {
    return __builtin_amdgcn_mfma_f32_32x32x16_bf16(a, b, c, 0, 0, 0);
}

// async global->LDS, 16B per lane; LDS dest = wave-uniform base + lane*16
__device__ __forceinline__ void gload16(const void* g, void* l) {
    __builtin_amdgcn_global_load_lds((const __attribute__((address_space(1))) u32*)g,
                                     (__attribute__((address_space(3))) u32*)l, 16, 0, 0);
}

// ---------------- fused prep kernel ----------------
// blocks [0,6144): cvt x fp32->bf16; [6144,6576): transpose W_attn; [6576,6720): transpose W_proj
__global__ __launch_bounds__(256)
void prep(const float* __restrict__ x, const float* __restrict__ Wa, const float* __restrict__ Wp,
          bf16* __restrict__ xb, bf16* __restrict__ Wab, bf16* __restrict__ Wpb) {
    __shared__ float tile[64][65];
    int blk = blockIdx.x, tid = threadIdx.x;
    if (blk < 6144) {
        int i = (blk * 256 + tid) * 4;
        float4 v = *(const float4*)(x + i);
        bf16x4 o;
        o[0] = (bf16)v.x; o[1] = (bf16)v.y; o[2] = (bf16)v.z; o[3] = (bf16)v.w;
        *(bf16x4*)(xb + i) = o;
        return;
    }
    const float* in; bf16* out; int C; int tile_id;
    if (blk < 6576) { in = Wa; out = Wab; C = 2304; tile_id = blk - 6144; }
    else            { in = Wp; out = Wpb; C = 768;  tile_id = blk - 6576; }
    const int R = 768;
    int tpr = C / 64;
    int tr = (tile_id / tpr) * 64, tc = (tile_id % tpr) * 64;
    int r0 = tid >> 4, c0 = (tid & 15) * 4;
    #pragma unroll
    for (int i = 0; i < 4; ++i) {
        float4 v = *(const float4*)&in[(long)(tr + r0 + i * 16) * C + tc + c0];
        tile[r0 + i * 16][c0 + 0] = v.x;
        tile[r0 + i * 16][c0 + 1] = v.y;
        tile[r0 + i * 16][c0 + 2] = v.z;
        tile[r0 + i * 16][c0 + 3] = v.w;
    }
    __syncthreads();
    int orr = (tid & 15) * 4;
    #pragma unroll
    for (int i = 0; i < 4; ++i) {
        int oc = (tid >> 4) + i * 16;
        bf16x4 o;
        #pragma unroll
        for (int j = 0; j < 4; ++j) o[j] = (bf16)tile[orr + j][oc];
        *(bf16x4*)&out[(long)(tc + oc) * R + tr + orr] = o;
    }
}

// ---------------- GEMM: BK=64, both-sides XOR swizzle. C = A[M,K]*Bt[N,K]^T + bias --------------
template<int MODE>
__global__ __launch_bounds__(256)
void gemm_bt(const bf16* __restrict__ A, const bf16* __restrict__ Bt,
             const float* __restrict__ bias,
             bf16* __restrict__ qo, bf16* __restrict__ ko, bf16* __restrict__ vto,
             float* __restrict__ outf,
             int M, int N, int K) {
    __shared__ bf16 As[128 * 64];
    __shared__ bf16 Bs[128 * 64];
    int tid = threadIdx.x;
    int wave = tid >> 6, lane = tid & 63;
    int wr = wave >> 1, wc = wave & 1;
    int lq = lane >> 4, lc = lane & 15;
    int mbase = blockIdx.x * 128, nbase = blockIdx.y * 128;
    int srow = wave * 32 + (lane >> 3);
    int scol = ((lane & 7) ^ (lane >> 3)) << 3;   // elems
    const bf16* aS = A  + (long)(mbase + srow) * K + scol;
    const bf16* bS = Bt + (long)(nbase + srow) * K + scol;
    char* AsB = (char*)As + wave * 4096;
    char* BsB = (char*)Bs + wave * 4096;
    f32x4 acc[4][4] = {};
    for (int kt = 0; kt < K; kt += 64) {
        #pragma unroll
        for (int j = 0; j < 4; ++j) {
            gload16(aS + kt + (long)j * 8 * K, AsB + j * 1024);
            gload16(bS + kt + (long)j * 8 * K, BsB + j * 1024);
        }
        __syncthreads();
        #pragma unroll
        for (int ksub = 0; ksub < 2; ++ksub) {
            bf16x8 af[4], bfr[4];
            #pragma unroll
            for (int mf = 0; mf < 4; ++mf) {
                int R = wr * 64 + mf * 16 + lc;
                af[mf]  = *(const bf16x8*)((char*)As + R * 128 + (((ksub * 4 + lq) ^ (lc & 7)) << 4));
            }
            #pragma unroll
            for (int nf = 0; nf < 4; ++nf) {
                int R = wc * 64 + nf * 16 + lc;
                bfr[nf] = *(const bf16x8*)((char*)Bs + R * 128 + (((ksub * 4 + lq) ^ (lc & 7)) << 4));
            }
            __builtin_amdgcn_s_setprio(1);
            #pragma unroll
            for (int mf = 0; mf < 4; ++mf)
                #pragma unroll
                for (int nf = 0; nf < 4; ++nf)
                    acc[mf][nf] = mfma16(af[mf], bfr[nf], acc[mf][nf]);
            __builtin_amdgcn_s_setprio(0);
        }
        __syncthreads();
    }
    #pragma unroll
    for (int mf = 0; mf < 4; ++mf) {
        #pragma unroll
        for (int nf = 0; nf < 4; ++nf) {
            int n = nbase + wc * 64 + nf * 16 + lc;
            float bv = bias[n];
            int m0 = mbase + wr * 64 + mf * 16 + lq * 4;
            if (MODE == 0) {
                int sect = n / 768, cc = n % 768;
                int h = cc >> 6, d = cc & 63;
                int b = m0 >> 11, t0 = m0 & 2047;
                long bh = (long)b * N_HEAD + h;
                if (sect == 0) {
                    #pragma unroll
                    for (int r = 0; r < 4; ++r)
                        qo[(bh * SEQ + t0 + r) * HD + d] = (bf16)((acc[mf][nf][r] + bv) * 0.18033688f);
                } else if (sect == 1) {
                    #pragma unroll
                    for (int r = 0; r < 4; ++r)
                        ko[(bh * SEQ + t0 + r) * HD + d] = (bf16)(acc[mf][nf][r] + bv);
                } else {
                    bf16x4 o;
                    #pragma unroll
                    for (int r = 0; r < 4; ++r) o[r] = (bf16)(acc[mf][nf][r] + bv);
                    *(bf16x4*)&vto[(bh * HD + d) * SEQ + t0] = o;
                }
            } else {
                #pragma unroll
                for (int r = 0; r < 4; ++r)
                    outf[(long)(m0 + r) * N + n] = acc[mf][nf][r] + bv;
            }
        }
    }
}

// ---------------- flash attention: DIRECT-GLOBAL K/V (no LDS staging, no loop barriers) ----------
// grid: (bh=x 0..47, tauR=y 0..31), tau = 31-tauR. 48%8==0 -> all blocks of a bh land on XCD bh%8,
// so per-XCD KV working set = 6 bh * 512KB = 3MB < 4MB L2: direct reads are L2-hits.
// Pair A (waves 0-1): KV tiles [0,half); pair B (waves 2-3): [half,nkt). Waves free-run (no sync);
// B parks (m,l,y) partials in LDS, single barrier, A merges and writes.
__global__ __launch_bounds__(256, 4)
void attn_kernel(const bf16* __restrict__ qg, const bf16* __restrict__ kg,
                 const bf16* __restrict__ vtg, bf16* __restrict__ yg) {
    __shared__ float ms[128 * 37];   // merge scratch, stride 37 (bank-spread), 18.9 KB
    int tid = threadIdx.x;
    int wave = tid >> 6, lane = tid & 63;
    int q5 = lane & 31, h = lane >> 5;
    int bh = blockIdx.x;
    int tau = gridDim.y - 1 - blockIdx.y;   // heavy blocks first
    int b = bh / N_HEAD, hh = bh % N_HEAD;
    int rh = wave & 1, wp = wave >> 1;
    int nkt  = tau + 1;
    int half = nkt >> 1;
    int base = wp ? half : 0;
    int cnt  = wp ? nkt - half : half;
    long koff = (long)bh * SEQ * HD;
    long voff = (long)bh * HD * SEQ;
    int qrow = tau * 64 + rh * 32 + q5;

    // Q B-frags (pre-scaled by 0.125*log2e): col q = lane&31, k(d) = s*16 + h*8 + 0..7
    bf16x8 qf[4];
    #pragma unroll
    for (int s = 0; s < 4; ++s)
        qf[s] = *(const bf16x8*)&qg[koff + (long)qrow * HD + s * 16 + h * 8];

    f32x16 y0 = {}, y1 = {};
    float m2 = -INFINITY, lsum = 0.f;

    for (int i = 0; i < cnt; ++i) {
        int tt = base + i;
        int k0 = tt * 64;
        const bf16* kp = kg + koff + (long)k0 * HD;
        const bf16* vp = vtg + voff + k0;
        // QK^T fragments straight from global (L2-hit): lane reads K rows q5 / 32+q5
        bf16x8 kf0[4], kf1[4];
        #pragma unroll
        for (int s = 0; s < 4; ++s) {
            kf0[s] = *(const bf16x8*)(kp + (long)q5 * HD + s * 16 + h * 8);
            kf1[s] = *(const bf16x8*)(kp + (long)(32 + q5) * HD + s * 16 + h * 8);
        }
        f32x16 s0 = {}, s1 = {};
        __builtin_amdgcn_s_setprio(1);
        #pragma unroll
        for (int s = 0; s < 4; ++s) {
            s0 = mfma32(kf0[s], qf[s], s0);
            s1 = mfma32(kf1[s], qf[s], s1);
        }
        __builtin_amdgcn_s_setprio(0);
        // V^T fragments (independent of softmax -> compiler hoists loads under it)
        bf16x8 v0[4], v1[4];
        #pragma unroll
        for (int s = 0; s < 4; ++s) {
            v0[s] = *(const bf16x8*)(vp + (long)q5 * SEQ + s * 16 + h * 8);
            v1[s] = *(const bf16x8*)(vp + (long)(32 + q5) * SEQ + s * 16 + h * 8);
        }
        if (tt == nkt - 1) {   // diagonal tile (always in pair B): causal mask
            #pragma unroll
            for (int r = 0; r < 16; ++r) {
                int ka = k0 + (r & 3) + 8 * (r >> 2) + 4 * h;
                if (ka > qrow)      s0[r] = -INFINITY;
                if (ka + 32 > qrow) s1[r] = -INFINITY;
            }
        }
        float pmax = s0[0];
        #pragma unroll
        for (int r = 1; r < 16; ++r) pmax = fmaxf(pmax, s0[r]);
        #pragma unroll
        for (int r = 0; r < 16; ++r) pmax = fmaxf(pmax, s1[r]);
        pmax = fmaxf(pmax, __shfl_xor(pmax, 32));
        if (!__all(pmax <= m2 + 11.5f)) {   // defer-max (base-2 units)
            float mnew = fmaxf(m2, pmax);
            float sc = __builtin_amdgcn_exp2f(m2 - mnew);
            #pragma unroll
            for (int r = 0; r < 16; ++r) { y0[r] *= sc; y1[r] *= sc; }
            lsum *= sc;
            m2 = mnew;
        }
        float psum = 0.f;
        u32 d0a[4], d1a[4], d0b[4], d1b[4];
        #pragma unroll
        for (int m = 0; m < 4; ++m) {
            union { bf16x4 v; u32 w[2]; } pa, pb;
            #pragma unroll
            for (int rr = 0; rr < 4; ++rr) {
                float p0 = __builtin_amdgcn_exp2f(s0[4 * m + rr] - m2);
                float p1 = __builtin_amdgcn_exp2f(s1[4 * m + rr] - m2);
                psum += p0 + p1;
                pa.v[rr] = (bf16)p0; pb.v[rr] = (bf16)p1;
            }
            d0a[m] = pa.w[0]; d1a[m] = pa.w[1];
            d0b[m] = pb.w[0]; d1b[m] = pb.w[1];
        }
        psum += __shfl_xor(psum, 32);
        lsum += psum;
        u32 e0a[4], e1a[4], e0b[4], e1b[4];
        #pragma unroll
        for (int m = 0; m < 4; ++m) {
            e0a[m] = __shfl_xor(d0a[m], 32); e1a[m] = __shfl_xor(d1a[m], 32);
            e0b[m] = __shfl_xor(d0b[m], 32); e1b[m] = __shfl_xor(d1b[m], 32);
        }
        // Y^T += V^T·P^T
        __builtin_amdgcn_s_setprio(1);
        #pragma unroll
        for (int s = 0; s < 4; ++s) {
            int m0 = 2 * (s & 1), m1 = m0 + 1;
            union { bf16x8 v; u32 w[4]; } fr;
            if (s < 2) {
                fr.w[0] = h ? e0a[m1] : d0a[m0];
                fr.w[1] = h ? e1a[m1] : d1a[m0];
                fr.w[2] = h ? d0a[m1] : e0a[m0];
                fr.w[3] = h ? d1a[m1] : e1a[m0];
            } else {
                fr.w[0] = h ? e0b[m1] : d0b[m0];
                fr.w[1] = h ? e1b[m1] : d1b[m0];
                fr.w[2] = h ? d0b[m1] : e0b[m0];
                fr.w[3] = h ? d1b[m1] : e1b[m0];
            }
            y0 = mfma32(v0[s], fr.v, y0);
            y1 = mfma32(v1[s], fr.v, y1);
        }
        __builtin_amdgcn_s_setprio(0);
    }

    // ----- merge partials: B parks in LDS, one barrier, A combines and writes -----
    int slot = (rh * 64 + lane) * 37;   // {0:m, 1:l, 2..17:y0, 18..33:y1}
    if (wp) {
        ms[slot] = m2; ms[slot + 1] = lsum;
        #pragma unroll
        for (int r = 0; r < 16; ++r) { ms[slot + 2 + r] = y0[r]; ms[slot + 18 + r] = y1[r]; }
    }
    __syncthreads();
    if (!wp) {
        float mB = ms[slot], lB = ms[slot + 1];
        float mf = fmaxf(m2, mB);
        float a  = __builtin_amdgcn_exp2f(m2 - mf);
        float bb = __builtin_amdgcn_exp2f(mB - mf);
        float inv = 1.f / (lsum * a + lB * bb);
        long rowoff = ((long)b * SEQ + qrow) * D_MODEL + (long)hh * HD;
        #pragma unroll
        for (int m = 0; m < 4; ++m) {
            bf16x4 o0, o1;
            #pragma unroll
            for (int rr = 0; rr < 4; ++rr) {
                o0[rr] = (bf16)((y0[4 * m + rr] * a + ms[slot + 2 + 4 * m + rr] * bb) * inv);
                o1[rr] = (bf16)((y1[4 * m + rr] * a + ms[slot + 18 + 4 * m + rr] * bb) * inv);
            }
            *(bf16x4*)&yg[rowoff + 8 * m + 4 * h]      = o0;
            *(bf16x4*)&yg[rowoff + 32 + 8 * m + 4 * h] = o1;
        }
    }
}

extern "C" void kernel_launch(void* const* d_in, const int* in_sizes, int n_in,
                              void* d_out, int out_size, void* d_ws, size_t ws_size,
                              hipStream_t stream) {
    const float* x      = (const float*)d_in[0];
    const float* W_attn = (const float*)d_in[1];
    const float* b_attn = (const float*)d_in[2];
    const float* W_proj = (const float*)d_in[3];
    const float* b_proj = (const float*)d_in[4];
    float* out = (float*)d_out;

    char* ws = (char*)d_ws;
    size_t off = 0;
    auto alloc = [&](size_t bytes) { void* p = ws + off; off += (bytes + 255) & ~255ULL; return p; };
    bf16* xb  = (bf16*)alloc(8192ULL * 768 * 2);
    bf16* Wab = (bf16*)alloc(2304ULL * 768 * 2);
    bf16* Wpb = (bf16*)alloc(768ULL * 768 * 2);
    bf16* qb_ = (bf16*)alloc((size_t)BH * SEQ * HD * 2);
    bf16* kb_ = (bf16*)alloc((size_t)BH * SEQ * HD * 2);
    bf16* vtb = (bf16*)alloc((size_t)BH * SEQ * HD * 2);
    bf16* yb  = (bf16*)alloc(8192ULL * 768 * 2);

    hipLaunchKernelGGL(prep, dim3(6720), dim3(256), 0, stream,
                       x, W_attn, W_proj, xb, Wab, Wpb);
    hipLaunchKernelGGL((gemm_bt<0>), dim3(64, 18), dim3(256), 0, stream,
                       xb, Wab, b_attn, qb_, kb_, vtb, (float*)nullptr, 8192, 2304, 768);
    hipLaunchKernelGGL(attn_kernel, dim3(48, 32), dim3(256), 0, stream,
                       qb_, kb_, vtb, yb);
    hipLaunchKernelGGL((gemm_bt<1>), dim3(64, 6), dim3(256), 0, stream,
                       yb, Wpb, b_proj, (bf16*)nullptr, (bf16*)nullptr, (bf16*)nullptr, out, 8192, 768, 768);
}

// Round 13
// 191.682 us; speedup vs baseline: 1.3702x; 1.3702x over previous
//
#include <hip/hip_runtime.h>
#include <hip/hip_bf16.h>
#include <math.h>

#define D_MODEL 768
#define N_HEAD  12
#define SEQ     2048
#define BATCH   4
#define HD      64
#define BH      (BATCH*N_HEAD)

typedef __bf16 bf16;
typedef __bf16 bf16x4 __attribute__((ext_vector_type(4)));
typedef __bf16 bf16x8 __attribute__((ext_vector_type(8)));
typedef float  f32x4  __attribute__((ext_vector_type(4)));
typedef float  f32x16 __attribute__((ext_vector_type(16)));
typedef unsigned int u32;

__device__ __forceinline__ f32x4 mfma16(bf16x8 a, bf16x8 b, f32x4 c) {
    return __builtin_amdgcn_mfma_f32_16x16x32_bf16(a, b, c, 0, 0, 0);
}
__device__ __forceinline__ f32x16 mfma32(bf16x8 a, bf16x8 b, f32x16 c) {
    return __builtin_amdgcn_mfma_f32_32x32x16_bf16(a, b, c, 0, 0, 0);
}

// async global->LDS, 16B per lane; LDS dest = wave-uniform base + lane*16
__device__ __forceinline__ void gload16(const void* g, void* l) {
    __builtin_amdgcn_global_load_lds((const __attribute__((address_space(1))) u32*)g,
                                     (__attribute__((address_space(3))) u32*)l, 16, 0, 0);
}

// ---------------- fused prep kernel ----------------
// blocks [0,6144): cvt x fp32->bf16; [6144,6576): transpose W_attn; [6576,6720): transpose W_proj
__global__ __launch_bounds__(256)
void prep(const float* __restrict__ x, const float* __restrict__ Wa, const float* __restrict__ Wp,
          bf16* __restrict__ xb, bf16* __restrict__ Wab, bf16* __restrict__ Wpb) {
    __shared__ float tile[64][65];
    int blk = blockIdx.x, tid = threadIdx.x;
    if (blk < 6144) {
        int i = (blk * 256 + tid) * 4;
        float4 v = *(const float4*)(x + i);
        bf16x4 o;
        o[0] = (bf16)v.x; o[1] = (bf16)v.y; o[2] = (bf16)v.z; o[3] = (bf16)v.w;
        *(bf16x4*)(xb + i) = o;
        return;
    }
    const float* in; bf16* out; int C; int tile_id;
    if (blk < 6576) { in = Wa; out = Wab; C = 2304; tile_id = blk - 6144; }
    else            { in = Wp; out = Wpb; C = 768;  tile_id = blk - 6576; }
    const int R = 768;
    int tpr = C / 64;
    int tr = (tile_id / tpr) * 64, tc = (tile_id % tpr) * 64;
    int r0 = tid >> 4, c0 = (tid & 15) * 4;
    #pragma unroll
    for (int i = 0; i < 4; ++i) {
        float4 v = *(const float4*)&in[(long)(tr + r0 + i * 16) * C + tc + c0];
        tile[r0 + i * 16][c0 + 0] = v.x;
        tile[r0 + i * 16][c0 + 1] = v.y;
        tile[r0 + i * 16][c0 + 2] = v.z;
        tile[r0 + i * 16][c0 + 3] = v.w;
    }
    __syncthreads();
    int orr = (tid & 15) * 4;
    #pragma unroll
    for (int i = 0; i < 4; ++i) {
        int oc = (tid >> 4) + i * 16;
        bf16x4 o;
        #pragma unroll
        for (int j = 0; j < 4; ++j) o[j] = (bf16)tile[orr + j][oc];
        *(bf16x4*)&out[(long)(tc + oc) * R + tr + orr] = o;
    }
}

// ---------------- GEMM: BK=64, both-sides XOR swizzle. C = A[M,K]*Bt[N,K]^T + bias --------------
template<int MODE>
__global__ __launch_bounds__(256)
void gemm_bt(const bf16* __restrict__ A, const bf16* __restrict__ Bt,
             const float* __restrict__ bias,
             bf16* __restrict__ qo, bf16* __restrict__ ko, bf16* __restrict__ vto,
             float* __restrict__ outf,
             int M, int N, int K) {
    __shared__ bf16 As[128 * 64];
    __shared__ bf16 Bs[128 * 64];
    int tid = threadIdx.x;
    int wave = tid >> 6, lane = tid & 63;
    int wr = wave >> 1, wc = wave & 1;
    int lq = lane >> 4, lc = lane & 15;
    int mbase = blockIdx.x * 128, nbase = blockIdx.y * 128;
    int srow = wave * 32 + (lane >> 3);
    int scol = ((lane & 7) ^ (lane >> 3)) << 3;   // elems
    const bf16* aS = A  + (long)(mbase + srow) * K + scol;
    const bf16* bS = Bt + (long)(nbase + srow) * K + scol;
    char* AsB = (char*)As + wave * 4096;
    char* BsB = (char*)Bs + wave * 4096;
    f32x4 acc[4][4] = {};
    for (int kt = 0; kt < K; kt += 64) {
        #pragma unroll
        for (int j = 0; j < 4; ++j) {
            gload16(aS + kt + (long)j * 8 * K, AsB + j * 1024);
            gload16(bS + kt + (long)j * 8 * K, BsB + j * 1024);
        }
        __syncthreads();
        #pragma unroll
        for (int ksub = 0; ksub < 2; ++ksub) {
            bf16x8 af[4], bfr[4];
            #pragma unroll
            for (int mf = 0; mf < 4; ++mf) {
                int R = wr * 64 + mf * 16 + lc;
                af[mf]  = *(const bf16x8*)((char*)As + R * 128 + (((ksub * 4 + lq) ^ (lc & 7)) << 4));
            }
            #pragma unroll
            for (int nf = 0; nf < 4; ++nf) {
                int R = wc * 64 + nf * 16 + lc;
                bfr[nf] = *(const bf16x8*)((char*)Bs + R * 128 + (((ksub * 4 + lq) ^ (lc & 7)) << 4));
            }
            __builtin_amdgcn_s_setprio(1);
            #pragma unroll
            for (int mf = 0; mf < 4; ++mf)
                #pragma unroll
                for (int nf = 0; nf < 4; ++nf)
                    acc[mf][nf] = mfma16(af[mf], bfr[nf], acc[mf][nf]);
            __builtin_amdgcn_s_setprio(0);
        }
        __syncthreads();
    }
    #pragma unroll
    for (int mf = 0; mf < 4; ++mf) {
        #pragma unroll
        for (int nf = 0; nf < 4; ++nf) {
            int n = nbase + wc * 64 + nf * 16 + lc;
            float bv = bias[n];
            int m0 = mbase + wr * 64 + mf * 16 + lq * 4;
            if (MODE == 0) {
                int sect = n / 768, cc = n % 768;
                int h = cc >> 6, d = cc & 63;
                int b = m0 >> 11, t0 = m0 & 2047;
                long bh = (long)b * N_HEAD + h;
                if (sect == 0) {
                    #pragma unroll
                    for (int r = 0; r < 4; ++r)
                        qo[(bh * SEQ + t0 + r) * HD + d] = (bf16)((acc[mf][nf][r] + bv) * 0.18033688f);
                } else if (sect == 1) {
                    #pragma unroll
                    for (int r = 0; r < 4; ++r)
                        ko[(bh * SEQ + t0 + r) * HD + d] = (bf16)(acc[mf][nf][r] + bv);
                } else {
                    bf16x4 o;
                    #pragma unroll
                    for (int r = 0; r < 4; ++r) o[r] = (bf16)(acc[mf][nf][r] + bv);
                    *(bf16x4*)&vto[(bh * HD + d) * SEQ + t0] = o;
                }
            } else {
                #pragma unroll
                for (int r = 0; r < 4; ++r)
                    outf[(long)(m0 + r) * N + n] = acc[mf][nf][r] + bv;
            }
        }
    }
}

// ---------------- flash attention: 32x32 MFMA, in-reg softmax, KV-SPLIT + in-block merge ----------
// grid: (bh 0..47, tauR 0..31), tau = 31-tauR (heavy first). Block = ONE 64-row q-tile, 4 waves.
// Pair A (waves 0-1): KV tiles [0,h); pair B (waves 2-3): [h,nkt). B parks partials in LDS, A merges.
// launch_bounds (256,4): VGPR cap 128 -> no spill (r9's (256,5) forced spills; r12's direct-global
// frag-reads also spilled + uncoalesced gathers: 130us. LDS staging + gload_lds is the right shape.)
__global__ __launch_bounds__(256, 4)
void attn_kernel(const bf16* __restrict__ qg, const bf16* __restrict__ kg,
                 const bf16* __restrict__ vtg, bf16* __restrict__ yg) {
    __shared__ __align__(16) bf16 KV[4][64 * 64];  // [2*wp+0]=K, [2*wp+1]=V ; 32 KB
    int tid = threadIdx.x;
    int wave = tid >> 6, lane = tid & 63;
    int q5 = lane & 31, h = lane >> 5;
    int bh = blockIdx.x;
    int tau = gridDim.y - 1 - blockIdx.y;   // heavy blocks first
    int b = bh / N_HEAD, hh = bh % N_HEAD;
    int rh = wave & 1, wp = wave >> 1;
    int nkt  = tau + 1;
    int half = nkt >> 1;
    int base = wp ? half : 0;
    int cnt  = wp ? nkt - half : half;
    int maxc = nkt - half;
    long koff = (long)bh * SEQ * HD;
    long voff = (long)bh * HD * SEQ;
    int qrow = tau * 64 + rh * 32 + q5;

    bf16x8 qf[4];
    #pragma unroll
    for (int s = 0; s < 4; ++s)
        qf[s] = *(const bf16x8*)&qg[koff + (long)qrow * HD + s * 16 + h * 8];

    f32x16 y0 = {}, y1 = {};
    float m2 = -INFINITY, lsum = 0.f;

    int srow0 = rh * 32 + (lane >> 3);
    int scolsw = ((lane & 7) ^ (lane >> 3)) << 3;
    int rsw = lane & 7;
    const char* KsC = (const char*)KV[2 * wp];
    const char* VsC = (const char*)KV[2 * wp + 1];

    for (int i = 0; i < maxc; ++i) {
        int tt = base + i;
        bool active = i < cnt;
        if (active) {
            int k0 = tt * 64;
            char* KsB = (char*)KV[2 * wp]     + rh * 4096;
            char* VsB = (char*)KV[2 * wp + 1] + rh * 4096;
            #pragma unroll
            for (int j = 0; j < 4; ++j) {
                gload16(kg + koff + (long)(k0 + srow0 + j * 8) * HD + scolsw,  KsB + j * 1024);
                gload16(vtg + voff + (long)(srow0 + j * 8) * SEQ + k0 + scolsw, VsB + j * 1024);
            }
        }
        __syncthreads();
        if (active) {
            int k0 = tt * 64;
            f32x16 s0 = {}, s1 = {};
            __builtin_amdgcn_s_setprio(1);
            #pragma unroll
            for (int s = 0; s < 4; ++s) {
                bf16x8 kf0 = *(const bf16x8*)(KsC + q5 * 128        + (((s * 2 + h) ^ rsw) << 4));
                bf16x8 kf1 = *(const bf16x8*)(KsC + (32 + q5) * 128 + (((s * 2 + h) ^ rsw) << 4));
                s0 = mfma32(kf0, qf[s], s0);
                s1 = mfma32(kf1, qf[s], s1);
            }
            __builtin_amdgcn_s_setprio(0);
            if (tt == nkt - 1) {
                #pragma unroll
                for (int r = 0; r < 16; ++r) {
                    int ka = k0 + (r & 3) + 8 * (r >> 2) + 4 * h;
                    if (ka > qrow)      s0[r] = -INFINITY;
                    if (ka + 32 > qrow) s1[r] = -INFINITY;
                }
            }
            float pmax = s0[0];
            #pragma unroll
            for (int r = 1; r < 16; ++r) pmax = fmaxf(pmax, s0[r]);
            #pragma unroll
            for (int r = 0; r < 16; ++r) pmax = fmaxf(pmax, s1[r]);
            pmax = fmaxf(pmax, __shfl_xor(pmax, 32));
            if (!__all(pmax <= m2 + 11.5f)) {
                float mnew = fmaxf(m2, pmax);
                float sc = __builtin_amdgcn_exp2f(m2 - mnew);
                #pragma unroll
                for (int r = 0; r < 16; ++r) { y0[r] *= sc; y1[r] *= sc; }
                lsum *= sc;
                m2 = mnew;
            }
            float psum = 0.f;
            u32 d0a[4], d1a[4], d0b[4], d1b[4];
            #pragma unroll
            for (int m = 0; m < 4; ++m) {
                union { bf16x4 v; u32 w[2]; } pa, pb;
                #pragma unroll
                for (int rr = 0; rr < 4; ++rr) {
                    float p0 = __builtin_amdgcn_exp2f(s0[4 * m + rr] - m2);
                    float p1 = __builtin_amdgcn_exp2f(s1[4 * m + rr] - m2);
                    psum += p0 + p1;
                    pa.v[rr] = (bf16)p0; pb.v[rr] = (bf16)p1;
                }
                d0a[m] = pa.w[0]; d1a[m] = pa.w[1];
                d0b[m] = pb.w[0]; d1b[m] = pb.w[1];
            }
            psum += __shfl_xor(psum, 32);
            lsum += psum;
            u32 e0a[4], e1a[4], e0b[4], e1b[4];
            #pragma unroll
            for (int m = 0; m < 4; ++m) {
                e0a[m] = __shfl_xor(d0a[m], 32); e1a[m] = __shfl_xor(d1a[m], 32);
                e0b[m] = __shfl_xor(d0b[m], 32); e1b[m] = __shfl_xor(d1b[m], 32);
            }
            __builtin_amdgcn_s_setprio(1);
            #pragma unroll
            for (int s = 0; s < 4; ++s) {
                int m0 = 2 * (s & 1), m1 = m0 + 1;
                union { bf16x8 v; u32 w[4]; } fr;
                if (s < 2) {
                    fr.w[0] = h ? e0a[m1] : d0a[m0];
                    fr.w[1] = h ? e1a[m1] : d1a[m0];
                    fr.w[2] = h ? d0a[m1] : e0a[m0];
                    fr.w[3] = h ? d1a[m1] : e1a[m0];
                } else {
                    fr.w[0] = h ? e0b[m1] : d0b[m0];
                    fr.w[1] = h ? e1b[m1] : d1b[m0];
                    fr.w[2] = h ? d0b[m1] : e0b[m0];
                    fr.w[3] = h ? d1b[m1] : e1b[m0];
                }
                bf16x8 v0 = *(const bf16x8*)(VsC + q5 * 128        + (((s * 2 + h) ^ rsw) << 4));
                bf16x8 v1 = *(const bf16x8*)(VsC + (32 + q5) * 128 + (((s * 2 + h) ^ rsw) << 4));
                y0 = mfma32(v0, fr.v, y0);
                y1 = mfma32(v1, fr.v, y1);
            }
            __builtin_amdgcn_s_setprio(0);
        }
        __syncthreads();
    }

    float* ms = (float*)&KV[0][0];
    int slot = (rh * 64 + lane) * 36;
    if (wp) {
        ms[slot] = m2; ms[slot + 1] = lsum;
        #pragma unroll
        for (int r = 0; r < 16; ++r) { ms[slot + 4 + r] = y0[r]; ms[slot + 20 + r] = y1[r]; }
    }
    __syncthreads();
    if (!wp) {
        float mB = ms[slot], lB = ms[slot + 1];
        float mf = fmaxf(m2, mB);
        float a  = __builtin_amdgcn_exp2f(m2 - mf);
        float bb = __builtin_amdgcn_exp2f(mB - mf);
        float inv = 1.f / (lsum * a + lB * bb);
        long rowoff = ((long)b * SEQ + qrow) * D_MODEL + (long)hh * HD;
        #pragma unroll
        for (int m = 0; m < 4; ++m) {
            bf16x4 o0, o1;
            #pragma unroll
            for (int rr = 0; rr < 4; ++rr) {
                o0[rr] = (bf16)((y0[4 * m + rr] * a + ms[slot + 4 + 4 * m + rr] * bb) * inv);
                o1[rr] = (bf16)((y1[4 * m + rr] * a + ms[slot + 20 + 4 * m + rr] * bb) * inv);
            }
            *(bf16x4*)&yg[rowoff + 8 * m + 4 * h]      = o0;
            *(bf16x4*)&yg[rowoff + 32 + 8 * m + 4 * h] = o1;
        }
    }
}

extern "C" void kernel_launch(void* const* d_in, const int* in_sizes, int n_in,
                              void* d_out, int out_size, void* d_ws, size_t ws_size,
                              hipStream_t stream) {
    const float* x      = (const float*)d_in[0];
    const float* W_attn = (const float*)d_in[1];
    const float* b_attn = (const float*)d_in[2];
    const float* W_proj = (const float*)d_in[3];
    const float* b_proj = (const float*)d_in[4];
    float* out = (float*)d_out;

    char* ws = (char*)d_ws;
    size_t off = 0;
    auto alloc = [&](size_t bytes) { void* p = ws + off; off += (bytes + 255) & ~255ULL; return p; };
    bf16* xb  = (bf16*)alloc(8192ULL * 768 * 2);
    bf16* Wab = (bf16*)alloc(2304ULL * 768 * 2);
    bf16* Wpb = (bf16*)alloc(768ULL * 768 * 2);
    bf16* qb_ = (bf16*)alloc((size_t)BH * SEQ * HD * 2);
    bf16* kb_ = (bf16*)alloc((size_t)BH * SEQ * HD * 2);
    bf16* vtb = (bf16*)alloc((size_t)BH * SEQ * HD * 2);
    bf16* yb  = (bf16*)alloc(8192ULL * 768 * 2);

    hipLaunchKernelGGL(prep, dim3(6720), dim3(256), 0, stream,
                       x, W_attn, W_proj, xb, Wab, Wpb);
    hipLaunchKernelGGL((gemm_bt<0>), dim3(64, 18), dim3(256), 0, stream,
                       xb, Wab, b_attn, qb_, kb_, vtb, (float*)nullptr, 8192, 2304, 768);
    hipLaunchKernelGGL(attn_kernel, dim3(48, 32), dim3(256), 0, stream,
                       qb_, kb_, vtb, yb);
    hipLaunchKernelGGL((gemm_bt<1>), dim3(64, 6), dim3(256), 0, stream,
                       yb, Wpb, b_proj, (bf16*)nullptr, (bf16*)nullptr, (bf16*)nullptr, out, 8192, 768, 768);
}